// Round 7
// baseline (79.656 us; speedup 1.0000x reference)
//
#include <hip/hip_runtime.h>
#include <hip/hip_bf16.h>

#define N_  4
#define C_  64
#define H_  28
#define W_  60
#define ZC_ 200
#define YC_ 8
#define XC_ 200
#define OUTC_ 128
#define KD_ 512            // C_*YC_
#define EPS_ 1e-6f
#define ZB 4               // z slices per block
#define XB 8               // x positions per block
#define NCOL 32            // ZB*XB columns per block

typedef __attribute__((ext_vector_type(8))) short short8;
typedef __attribute__((ext_vector_type(4))) float f32x4;

__device__ __forceinline__ unsigned short f2bf(float f) {
    unsigned int u = __float_as_uint(f);
    u += 0x7FFF + ((u >> 16) & 1);   // round-to-nearest-even
    return (unsigned short)(u >> 16);
}

// ---------------------------------------------------------------------------
// Prep: featB[n][h][w][c] = bf16(img[n][c][h][w])  (channels-last, bf16)
//       Wb[o][y*64+c]     = bf16(W[o][c*8+y])      (y-major k, bf16)
// ---------------------------------------------------------------------------
__global__ void gsvt_prep(const float* __restrict__ img,
                          const float* __restrict__ Wc,
                          unsigned short* __restrict__ featB,
                          unsigned short* __restrict__ Wb) {
    int tid = blockIdx.x * blockDim.x + threadIdx.x;
    int stride = gridDim.x * blockDim.x;
    const int totF = N_ * H_ * W_ * C_;       // 430080
    for (int i = tid; i < totF; i += stride) {
        int c  = i & 63;
        int hw = i >> 6;
        int w  = hw % W_;
        int nh = hw / W_;
        int h  = nh % H_;
        int n  = nh / H_;
        featB[i] = f2bf(img[((n * C_ + c) * H_ + h) * W_ + w]);
    }
    const int totW = OUTC_ * KD_;             // 65536
    for (int i = tid; i < totW; i += stride) {
        int k = i & (KD_ - 1);
        int o = i >> 9;
        int y = k >> 6;
        int c = k & 63;
        Wb[i] = f2bf(Wc[o * KD_ + c * YC_ + y]);
    }
}

__device__ __forceinline__ void acc8(float* num, const uint4 V, const float w) {
    num[0] += w * __uint_as_float(V.x << 16);
    num[1] += w * __uint_as_float(V.x & 0xFFFF0000u);
    num[2] += w * __uint_as_float(V.y << 16);
    num[3] += w * __uint_as_float(V.y & 0xFFFF0000u);
    num[4] += w * __uint_as_float(V.z << 16);
    num[5] += w * __uint_as_float(V.z & 0xFFFF0000u);
    num[6] += w * __uint_as_float(V.w << 16);
    num[7] += w * __uint_as_float(V.w & 0xFFFF0000u);
}

// ===========================================================================
// Fused: per-z-slice weight precompute + gather into LDS redB + in-block GEMM
// Grid: (XC_/XB = 25, ZC_/ZB = 50), block 256.  No ragged edges.
// ===========================================================================
__global__ __launch_bounds__(256, 4) void gsvt_fused32(
        const float* __restrict__ coords,        // (N, ZC, YC, XC, 3)
        const float* __restrict__ validm,        // (N, ZC, YC, XC)
        const unsigned short* __restrict__ featB,// (N, H, W, C) bf16
        const unsigned short* __restrict__ Wb,   // (OUTC, 512) bf16, y-major k
        const float* __restrict__ bias,          // (OUTC)
        float* __restrict__ out)                 // (OUTC, ZC, XC)
{
    __shared__ float4 wq[256];                   // [cam][64 pairs], 4 KB
    __shared__ uint2  off[256];                  // 2 KB
    __shared__ float  ms[64][4];                 // 1 KB
    __shared__ unsigned short redB[64][NCOL][8]; // 32 KB

    const int z0 = blockIdx.y * ZB;
    const int x0 = blockIdx.x * XB;
    const int t  = threadIdx.x;

    const int grp   = t >> 3;    // 0..31
    const int lane8 = t & 7;
    const unsigned lb = (unsigned)(lane8 << 4);
    const char* fb = (const char*)featB;

    // phase0 thread mapping: one (cam, pair) item per thread per pass
    const int cam = t >> 6;      // 0..3 (wave-uniform)
    const int p   = t & 63;      // pair = y*8 + xl
    const int py0 = p >> 3, pxl0 = p & 7;

    for (int pass = 0; pass < ZB; ++pass) {
        const int zs = z0 + pass;

        // ---- phase 0a: load coords + mask ----
        const int cb = ((cam * ZC_ + zs) * YC_ + py0) * XC_ + x0 + pxl0;
        const float m  = validm[cb];
        const float gx = coords[cb * 3 + 0];
        const float gy = coords[cb * 3 + 1];
        const float gz = coords[cb * 3 + 2];
        ms[p][cam] = m;
        __syncthreads();

        // ---- phase 0b: weights (mask, z-weight, 1/den folded) + offsets ----
        {
            const float inv = 1.0f / (ms[p][0] + ms[p][1] + ms[p][2] + ms[p][3] + EPS_);
            const float xf = ((gx + 1.0f) * (float)W_ - 1.0f) * 0.5f;
            const float yf = ((gy + 1.0f) * (float)H_ - 1.0f) * 0.5f;
            const float zf = gz * 0.5f;
            const float x0f = floorf(xf), y0f = floorf(yf), z0f = floorf(zf);
            const float wx = xf - x0f, wy = yf - y0f, wz = zf - z0f;
            const int xi = (int)x0f, yi = (int)y0f, zi = (int)z0f;

            const float zw = (zi == 0) ? (1.f - wz) : ((zi == -1) ? wz : 0.f);
            const float s  = m * zw * inv;

            const float wx0 = (xi >= 0 && xi < W_)         ? (1.f - wx) * s : 0.f;
            const float wx1 = (xi + 1 >= 0 && xi + 1 < W_) ? wx * s         : 0.f;
            const float wy0 = (yi >= 0 && yi < H_)         ? (1.f - wy)     : 0.f;
            const float wy1 = (yi + 1 >= 0 && yi + 1 < H_) ? wy             : 0.f;

            wq[t] = make_float4(wy0 * wx0, wy0 * wx1, wy1 * wx0, wy1 * wx1);

            const int xc0 = min(max(xi, 0), W_ - 1);
            const int xc1 = min(max(xi + 1, 0), W_ - 1);
            const int yc0 = min(max(yi, 0), H_ - 1);
            const int yc1 = min(max(yi + 1, 0), H_ - 1);
            const unsigned base = (unsigned)((((cam * H_ + yc0) * W_) + xc0) * 128);
            const unsigned dxo  = (unsigned)((xc1 - xc0) * 128);
            const unsigned dyo  = (unsigned)((yc1 - yc0) * W_ * 128);
            off[t] = make_uint2(base, dxo | (dyo << 16));
        }
        __syncthreads();

        // ---- sample: 32 groups of 8 lanes; 2 pairs per group this pass ----
        #pragma unroll
        for (int half = 0; half < 2; ++half) {
            const int pp  = grp + 32 * half;     // 0..63
            const int py  = pp >> 3, pxl = pp & 7;

            float num[8] = {0.f,0.f,0.f,0.f,0.f,0.f,0.f,0.f};

            #pragma unroll
            for (int n = 0; n < N_; ++n) {
                const float4 w4 = wq[n * 64 + pp];
                if (w4.x + w4.y + w4.z + w4.w > 0.f) {
                    const uint2 oo = off[n * 64 + pp];
                    const unsigned base = oo.x + lb;
                    const unsigned dxo = oo.y & 0xFFFFu;
                    const unsigned dyo = oo.y >> 16;
                    const uint4 V0 = *(const uint4*)(fb + base);
                    const uint4 V1 = *(const uint4*)(fb + (base + dxo));
                    const uint4 V2 = *(const uint4*)(fb + (base + dyo));
                    const uint4 V3 = *(const uint4*)(fb + (base + dyo + dxo));
                    acc8(num, V0, w4.x);
                    acc8(num, V1, w4.y);
                    acc8(num, V2, w4.z);
                    acc8(num, V3, w4.w);
                }
            }

            unsigned r0, r1, r2, r3;
            asm("v_cvt_pk_bf16_f32 %0, %1, %2" : "=v"(r0) : "v"(num[0]), "v"(num[1]));
            asm("v_cvt_pk_bf16_f32 %0, %1, %2" : "=v"(r1) : "v"(num[2]), "v"(num[3]));
            asm("v_cvt_pk_bf16_f32 %0, %1, %2" : "=v"(r2) : "v"(num[4]), "v"(num[5]));
            asm("v_cvt_pk_bf16_f32 %0, %1, %2" : "=v"(r3) : "v"(num[6]), "v"(num[7]));

            // k = y*64 + lane8*8 + j  ->  kb = y*8+lane8
            const int kb   = py * 8 + lane8;
            const int col  = pass * 8 + pxl;          // 0..31
            const int pcol = col ^ (kb & 15);         // XOR swizzle within 16-block
            *(uint4*)&redB[kb][pcol][0] = make_uint4(r0, r1, r2, r3);
        }
        __syncthreads();   // redB/tables settled before next pass overwrites tables
    }

    // ---- GEMM: C[128,32] = Wb[128,512] * redB[512,32] ----
    const int wave = t >> 6;        // 0..3
    const int lane = t & 63;
    const int q    = lane >> 4;     // 0..3
    const int l16  = lane & 15;

    const int ct = wave & 1;        // column tile (16 cols)
    const int rg = wave >> 1;       // row group (64 rows)

    f32x4 acc[4] = {{0.f,0.f,0.f,0.f},{0.f,0.f,0.f,0.f},
                    {0.f,0.f,0.f,0.f},{0.f,0.f,0.f,0.f}};

    #pragma unroll
    for (int ks = 0; ks < 16; ++ks) {
        const int kb = ks * 4 + q;
        const short8 Bf = *(const short8*)&redB[kb][ct * 16 + (l16 ^ (kb & 15))][0];
        #pragma unroll
        for (int mt = 0; mt < 4; ++mt) {
            const int row = rg * 64 + mt * 16 + l16;
            const short8 Af = *(const short8*)(Wb + row * KD_ + ks * 32 + q * 8);
            acc[mt] = __builtin_amdgcn_mfma_f32_16x16x32_bf16(Af, Bf, acc[mt], 0, 0, 0);
        }
    }

    const int col = ct * 16 + l16;      // 0..31
    const int zz  = col >> 3;           // 0..3
    const int xl  = col & 7;
    const int obase = (z0 + zz) * XC_ + x0 + xl;
    #pragma unroll
    for (int mt = 0; mt < 4; ++mt) {
        #pragma unroll
        for (int j = 0; j < 4; ++j) {
            const int o = rg * 64 + mt * 16 + q * 4 + j;
            out[o * (ZC_ * XC_) + obase] = acc[mt][j] + bias[o];
        }
    }
}

extern "C" void kernel_launch(void* const* d_in, const int* in_sizes, int n_in,
                              void* d_out, int out_size, void* d_ws, size_t ws_size,
                              hipStream_t stream) {
    const float* coords = (const float*)d_in[0];   // (1,4,200,8,200,3)
    const float* validm = (const float*)d_in[1];   // (1,4,200,8,200,1)
    const float* img    = (const float*)d_in[2];   // (1,4,64,28,60)
    const float* Wc     = (const float*)d_in[3];   // (128, 512)
    const float* bias   = (const float*)d_in[4];   // (128)
    float* out = (float*)d_out;                    // (1,1,128,200,200)

    unsigned short* featB = (unsigned short*)d_ws;           // 430080 bf16
    unsigned short* Wb    = featB + (N_ * H_ * W_ * C_);     // 65536 bf16

    gsvt_prep<<<512, 256, 0, stream>>>(img, Wc, featB, Wb);

    dim3 grid(XC_ / XB, ZC_ / ZB);   // (25, 50)
    gsvt_fused32<<<grid, 256, 0, stream>>>(coords, validm, featB, Wb, bias, out);
}

// Round 8
// 63.955 us; speedup vs baseline: 1.2455x; 1.2455x over previous
//
#include <hip/hip_runtime.h>
#include <hip/hip_bf16.h>
#include <hip/hip_fp16.h>

#define N_  4
#define C_  64
#define H_  28
#define W_  60
#define ZC_ 200
#define YC_ 8
#define XC_ 200
#define OUTC_ 128
#define KD_ 512            // C_*YC_
#define EPS_ 1e-6f
#define ZB 4               // z slices per block
#define XB 8               // x positions per block
#define NCOL 32            // ZB*XB columns per block

typedef __attribute__((ext_vector_type(8))) short short8;
typedef __attribute__((ext_vector_type(4))) float f32x4;

__device__ __forceinline__ unsigned short f2bf(float f) {
    unsigned int u = __float_as_uint(f);
    u += 0x7FFF + ((u >> 16) & 1);   // round-to-nearest-even
    return (unsigned short)(u >> 16);
}

// ---------------------------------------------------------------------------
// Prep: featB[n][h][w][c] = bf16(img[n][c][h][w])  (channels-last, bf16)
//       Wb[o][y*64+c]     = bf16(W[o][c*8+y])      (y-major k, bf16)
// ---------------------------------------------------------------------------
__global__ void gsvt_prep(const float* __restrict__ img,
                          const float* __restrict__ Wc,
                          unsigned short* __restrict__ featB,
                          unsigned short* __restrict__ Wb) {
    int tid = blockIdx.x * blockDim.x + threadIdx.x;
    int stride = gridDim.x * blockDim.x;
    const int totF = N_ * H_ * W_ * C_;       // 430080
    for (int i = tid; i < totF; i += stride) {
        int c  = i & 63;
        int hw = i >> 6;
        int w  = hw % W_;
        int nh = hw / W_;
        int h  = nh % H_;
        int n  = nh / H_;
        featB[i] = f2bf(img[((n * C_ + c) * H_ + h) * W_ + w]);
    }
    const int totW = OUTC_ * KD_;             // 65536
    for (int i = tid; i < totW; i += stride) {
        int k = i & (KD_ - 1);
        int o = i >> 9;
        int y = k >> 6;
        int c = k & 63;
        Wb[i] = f2bf(Wc[o * KD_ + c * YC_ + y]);
    }
}

// float2 accumulate of one corner (8 channels in uint4), weight w broadcast.
// Written as float2 math so the compiler can emit v_pk_fma_f32.
__device__ __forceinline__ void accp(float2* n, const uint4 V, const float w) {
    float2 f0, f1, f2, f3;
    f0.x = __uint_as_float(V.x << 16); f0.y = __uint_as_float(V.x & 0xFFFF0000u);
    f1.x = __uint_as_float(V.y << 16); f1.y = __uint_as_float(V.y & 0xFFFF0000u);
    f2.x = __uint_as_float(V.z << 16); f2.y = __uint_as_float(V.z & 0xFFFF0000u);
    f3.x = __uint_as_float(V.w << 16); f3.y = __uint_as_float(V.w & 0xFFFF0000u);
    n[0].x += w * f0.x; n[0].y += w * f0.y;
    n[1].x += w * f1.x; n[1].y += w * f1.y;
    n[2].x += w * f2.x; n[2].y += w * f2.y;
    n[3].x += w * f3.x; n[3].y += w * f3.y;
}

// ===========================================================================
// Fused, single-pass tables: phase0 (all 32 cols) -> long sampling phase ->
// in-block GEMM C[128,32] = Wb[128,512] * redB[512,32].
// Grid: (XC_/XB = 25, ZC_/ZB = 50), block 256.  No ragged edges.
// ===========================================================================
__global__ __launch_bounds__(256, 3) void gsvt_fused1p(
        const float* __restrict__ coords,        // (N, ZC, YC, XC, 3)
        const float* __restrict__ validm,        // (N, ZC, YC, XC)
        const unsigned short* __restrict__ featB,// (N, H, W, C) bf16
        const unsigned short* __restrict__ Wb,   // (OUTC, 512) bf16, y-major k
        const float* __restrict__ bias,          // (OUTC)
        float* __restrict__ out)                 // (OUTC, ZC, XC)
{
    // tab[cam*256 + p] = { w00|w01 (f16x2), w10|w11 (f16x2), base, dx|dy<<16 }
    __shared__ uint4 tab[N_ * 256];              // 16 KB
    __shared__ unsigned short redB[64][NCOL][8]; // 32 KB
    float (*ms)[4] = (float(*)[4])&redB[0][0][0];  // 4 KB alias, dead before redB

    const int z0 = blockIdx.y * ZB;
    const int x0 = blockIdx.x * XB;
    const int t  = threadIdx.x;

    // ---- phase 0a: one (pair) per thread; p = y*32 + col, col = zz*8+xl ----
    const int p0   = t;
    const int y0_  = t >> 5;         // 0..7
    const int col0 = t & 31;         // 0..31
    const int zg   = z0 + (col0 >> 3);
    const int xg   = x0 + (col0 & 7);

    float gx[4], gy[4], gzv[4], mm[4];
    #pragma unroll
    for (int cam = 0; cam < N_; ++cam) {
        const int cb = ((cam * ZC_ + zg) * YC_ + y0_) * XC_ + xg;
        gx[cam]  = coords[cb * 3 + 0];
        gy[cam]  = coords[cb * 3 + 1];
        gzv[cam] = coords[cb * 3 + 2];
        mm[cam]  = validm[cb];
        ms[p0][cam] = mm[cam];
    }
    __syncthreads();

    // ---- phase 0b: weights (mask, z-weight, 1/den folded) + offsets ----
    {
        const float inv = 1.0f / (ms[p0][0] + ms[p0][1] + ms[p0][2] + ms[p0][3] + EPS_);
        #pragma unroll
        for (int cam = 0; cam < N_; ++cam) {
            const float xf = ((gx[cam] + 1.0f) * (float)W_ - 1.0f) * 0.5f;
            const float yf = ((gy[cam] + 1.0f) * (float)H_ - 1.0f) * 0.5f;
            const float zf = gzv[cam] * 0.5f;
            const float x0f = floorf(xf), y0f = floorf(yf), z0f = floorf(zf);
            const float wx = xf - x0f, wy = yf - y0f, wz = zf - z0f;
            const int xi = (int)x0f, yi = (int)y0f, zi = (int)z0f;

            const float zw = (zi == 0) ? (1.f - wz) : ((zi == -1) ? wz : 0.f);
            const float s  = mm[cam] * zw * inv;

            const float wx0 = (xi >= 0 && xi < W_)         ? (1.f - wx) * s : 0.f;
            const float wx1 = (xi + 1 >= 0 && xi + 1 < W_) ? wx * s         : 0.f;
            const float wy0 = (yi >= 0 && yi < H_)         ? (1.f - wy)     : 0.f;
            const float wy1 = (yi + 1 >= 0 && yi + 1 < H_) ? wy             : 0.f;

            const float w00 = wy0 * wx0, w01 = wy0 * wx1;
            const float w10 = wy1 * wx0, w11 = wy1 * wx1;

            const unsigned hlo = (unsigned)__half_as_ushort(__float2half_rn(w00))
                               | ((unsigned)__half_as_ushort(__float2half_rn(w01)) << 16);
            const unsigned hhi = (unsigned)__half_as_ushort(__float2half_rn(w10))
                               | ((unsigned)__half_as_ushort(__float2half_rn(w11)) << 16);

            const int xc0 = min(max(xi, 0), W_ - 1);
            const int xc1 = min(max(xi + 1, 0), W_ - 1);
            const int yc0 = min(max(yi, 0), H_ - 1);
            const int yc1 = min(max(yi + 1, 0), H_ - 1);
            const unsigned base = (unsigned)((((cam * H_ + yc0) * W_) + xc0) * 128);
            const unsigned dxo  = (unsigned)((xc1 - xc0) * 128);          // 0 or 128
            const unsigned dyo  = (unsigned)((yc1 - yc0) * W_ * 128);     // 0 or 7680
            tab[cam * 256 + p0] = make_uint4(hlo, hhi, base, dxo | (dyo << 16));
        }
    }
    __syncthreads();

    // ---- sampling: group (8 lanes) = one column; iterate y = 0..7 ----
    const int grp   = t >> 3;        // 0..31  == column
    const int lane8 = t & 7;
    const unsigned lb = (unsigned)(lane8 << 4);
    const char* fb = (const char*)featB;

    #pragma unroll
    for (int y = 0; y < YC_; ++y) {
        const int p = y * 32 + grp;

        float2 num[4] = {{0.f,0.f},{0.f,0.f},{0.f,0.f},{0.f,0.f}};

        #pragma unroll
        for (int cam = 0; cam < N_; ++cam) {
            const uint4 T = tab[cam * 256 + p];
            if (T.x | T.y) {
                const float2 wlo = __half22float2(*(const __half2*)&T.x); // (w00,w01)
                const float2 whi = __half22float2(*(const __half2*)&T.y); // (w10,w11)
                const unsigned base = T.z + lb;
                const unsigned dxo = T.w & 0xFFFFu;
                const unsigned dyo = T.w >> 16;
                const uint4 V0 = *(const uint4*)(fb + base);
                const uint4 V1 = *(const uint4*)(fb + (base + dxo));
                const uint4 V2 = *(const uint4*)(fb + (base + dyo));
                const uint4 V3 = *(const uint4*)(fb + (base + dyo + dxo));
                accp(num, V0, wlo.x);
                accp(num, V1, wlo.y);
                accp(num, V2, whi.x);
                accp(num, V3, whi.y);
            }
        }

        unsigned r0, r1, r2, r3;
        asm("v_cvt_pk_bf16_f32 %0, %1, %2" : "=v"(r0) : "v"(num[0].x), "v"(num[0].y));
        asm("v_cvt_pk_bf16_f32 %0, %1, %2" : "=v"(r1) : "v"(num[1].x), "v"(num[1].y));
        asm("v_cvt_pk_bf16_f32 %0, %1, %2" : "=v"(r2) : "v"(num[2].x), "v"(num[2].y));
        asm("v_cvt_pk_bf16_f32 %0, %1, %2" : "=v"(r3) : "v"(num[3].x), "v"(num[3].y));

        // k = y*64 + lane8*8 + j  ->  kb = y*8+lane8
        const int kb   = y * 8 + lane8;
        const int pcol = (grp & 16) | ((grp ^ kb) & 15);   // XOR swizzle in 16-block
        *(uint4*)&redB[kb][pcol][0] = make_uint4(r0, r1, r2, r3);
    }
    __syncthreads();

    // ---- GEMM: C[128,32] = Wb[128,512] * redB[512,32] ----
    const int wave = t >> 6;        // 0..3 -> rows [wave*32, +32)
    const int lane = t & 63;
    const int q    = lane >> 4;     // 0..3
    const int l16  = lane & 15;

    f32x4 acc00 = {0.f,0.f,0.f,0.f}, acc01 = {0.f,0.f,0.f,0.f};
    f32x4 acc10 = {0.f,0.f,0.f,0.f}, acc11 = {0.f,0.f,0.f,0.f};
    const unsigned short* wbase = Wb + (wave * 32 + l16) * KD_;

    #pragma unroll
    for (int ks = 0; ks < 16; ++ks) {
        const int kb = ks * 4 + q;
        const int xs = l16 ^ (kb & 15);
        const short8 B0 = *(const short8*)&redB[kb][xs][0];
        const short8 B1 = *(const short8*)&redB[kb][16 + xs][0];
        const short8 A0 = *(const short8*)(wbase + ks * 32 + q * 8);
        const short8 A1 = *(const short8*)(wbase + 16 * KD_ + ks * 32 + q * 8);
        acc00 = __builtin_amdgcn_mfma_f32_16x16x32_bf16(A0, B0, acc00, 0, 0, 0);
        acc01 = __builtin_amdgcn_mfma_f32_16x16x32_bf16(A0, B1, acc01, 0, 0, 0);
        acc10 = __builtin_amdgcn_mfma_f32_16x16x32_bf16(A1, B0, acc10, 0, 0, 0);
        acc11 = __builtin_amdgcn_mfma_f32_16x16x32_bf16(A1, B1, acc11, 0, 0, 0);
    }

    #pragma unroll
    for (int ct = 0; ct < 2; ++ct) {
        const int col = ct * 16 + l16;
        const int zz  = col >> 3;
        const int xl  = col & 7;
        const int ob  = (z0 + zz) * XC_ + x0 + xl;
        const f32x4 a0 = ct ? acc01 : acc00;
        const f32x4 a1 = ct ? acc11 : acc10;
        #pragma unroll
        for (int j = 0; j < 4; ++j) {
            const int o0 = wave * 32 + q * 4 + j;
            out[o0 * (ZC_ * XC_) + ob] = a0[j] + bias[o0];
            const int o1 = o0 + 16;
            out[o1 * (ZC_ * XC_) + ob] = a1[j] + bias[o1];
        }
    }
}

extern "C" void kernel_launch(void* const* d_in, const int* in_sizes, int n_in,
                              void* d_out, int out_size, void* d_ws, size_t ws_size,
                              hipStream_t stream) {
    const float* coords = (const float*)d_in[0];   // (1,4,200,8,200,3)
    const float* validm = (const float*)d_in[1];   // (1,4,200,8,200,1)
    const float* img    = (const float*)d_in[2];   // (1,4,64,28,60)
    const float* Wc     = (const float*)d_in[3];   // (128, 512)
    const float* bias   = (const float*)d_in[4];   // (128)
    float* out = (float*)d_out;                    // (1,1,128,200,200)

    unsigned short* featB = (unsigned short*)d_ws;           // 430080 bf16
    unsigned short* Wb    = featB + (N_ * H_ * W_ * C_);     // 65536 bf16

    gsvt_prep<<<512, 256, 0, stream>>>(img, Wc, featB, Wb);

    dim3 grid(XC_ / XB, ZC_ / ZB);   // (25, 50)
    gsvt_fused1p<<<grid, 256, 0, stream>>>(coords, validm, featB, Wb, bias, out);
}

// Round 9
// 56.119 us; speedup vs baseline: 1.4194x; 1.1396x over previous
//
#include <hip/hip_runtime.h>
#include <hip/hip_bf16.h>
#include <hip/hip_fp16.h>

#define N_  4
#define C_  64
#define H_  28
#define W_  60
#define ZC_ 200
#define YC_ 8
#define XC_ 200
#define OUTC_ 128
#define KD_ 512            // C_*YC_
#define EPS_ 1e-6f
#define ZB 4               // z slices per block
#define XB 8               // x positions per block
#define NCOL 32            // ZB*XB columns per block

typedef __attribute__((ext_vector_type(8))) short short8;
typedef __attribute__((ext_vector_type(4))) float f32x4;

__device__ __forceinline__ unsigned short f2bf(float f) {
    unsigned int u = __float_as_uint(f);
    u += 0x7FFF + ((u >> 16) & 1);   // round-to-nearest-even
    return (unsigned short)(u >> 16);
}

// ---------------------------------------------------------------------------
// Prep: featB[n][h][w][c] = bf16(img[n][c][h][w])  (channels-last, bf16)
//       Wb[o][y*64+c]     = bf16(W[o][c*8+y])      (y-major k, bf16)
// ---------------------------------------------------------------------------
__global__ void gsvt_prep(const float* __restrict__ img,
                          const float* __restrict__ Wc,
                          unsigned short* __restrict__ featB,
                          unsigned short* __restrict__ Wb) {
    int tid = blockIdx.x * blockDim.x + threadIdx.x;
    int stride = gridDim.x * blockDim.x;
    const int totF = N_ * H_ * W_ * C_;       // 430080
    for (int i = tid; i < totF; i += stride) {
        int c  = i & 63;
        int hw = i >> 6;
        int w  = hw % W_;
        int nh = hw / W_;
        int h  = nh % H_;
        int n  = nh / H_;
        featB[i] = f2bf(img[((n * C_ + c) * H_ + h) * W_ + w]);
    }
    const int totW = OUTC_ * KD_;             // 65536
    for (int i = tid; i < totW; i += stride) {
        int k = i & (KD_ - 1);
        int o = i >> 9;
        int y = k >> 6;
        int c = k & 63;
        Wb[i] = f2bf(Wc[o * KD_ + c * YC_ + y]);
    }
}

// float2 accumulate of one corner (8 channels in uint4), weight w broadcast.
__device__ __forceinline__ void accp(float2* n, const uint4 V, const float w) {
    float2 f0, f1, f2, f3;
    f0.x = __uint_as_float(V.x << 16); f0.y = __uint_as_float(V.x & 0xFFFF0000u);
    f1.x = __uint_as_float(V.y << 16); f1.y = __uint_as_float(V.y & 0xFFFF0000u);
    f2.x = __uint_as_float(V.z << 16); f2.y = __uint_as_float(V.z & 0xFFFF0000u);
    f3.x = __uint_as_float(V.w << 16); f3.y = __uint_as_float(V.w & 0xFFFF0000u);
    n[0].x += w * f0.x; n[0].y += w * f0.y;
    n[1].x += w * f1.x; n[1].y += w * f1.y;
    n[2].x += w * f2.x; n[2].y += w * f2.y;
    n[3].x += w * f3.x; n[3].y += w * f3.y;
}

// ===========================================================================
// Fused: phase0 (8B-packed tables + activity masks) -> bit-iterated sampling
// -> in-block GEMM C[128,32] = Wb[128,512] * redB[512,32].
// Grid: (XC_/XB = 25, ZC_/ZB = 50), block 256.  LDS = 40.0 KB -> 4 blk/CU.
// ===========================================================================
__global__ __launch_bounds__(256, 4) void gsvt_fused2(
        const float* __restrict__ coords,        // (N, ZC, YC, XC, 3)
        const float* __restrict__ validm,        // (N, ZC, YC, XC)
        const unsigned short* __restrict__ featB,// (N, H, W, C) bf16
        const unsigned short* __restrict__ Wb,   // (OUTC, 512) bf16, y-major k
        const float* __restrict__ bias,          // (OUTC)
        float* __restrict__ out)                 // (OUTC, ZC, XC)
{
    // tab2 entry (8B): A = q00 | q01<<12 | q10.lo8<<24
    //                  B = q10.hi4 | q11<<4 | pixidx<<16 | fdx<<29 | fdy<<30
    // (qXX = unorm12 corner weights with mask, z-weight, 1/den folded in)
    __shared__ uint2 tab2[N_ * 256];             // 8 KB
    __shared__ unsigned short redB[64][NCOL][8]; // 32 KB
    float (*ms)[4] = (float(*)[4])&redB[0][0][0];                   // 4 KB alias
    unsigned* cmaskA = (unsigned*)((char*)&redB[0][0][0] + 4096);   // 128 B alias

    const int z0 = blockIdx.y * ZB;
    const int x0 = blockIdx.x * XB;
    const int t  = threadIdx.x;

    // ---- phase 0a: one pair per thread; p0 = y*32 + col, col = zz*8+xl ----
    const int p0   = t;
    const int y0_  = t >> 5;         // 0..7
    const int col0 = t & 31;         // 0..31
    const int zg   = z0 + (col0 >> 3);
    const int xg   = x0 + (col0 & 7);

    if (t < NCOL) cmaskA[t] = 0u;

    float gx[4], gy[4], gzv[4], mm[4];
    #pragma unroll
    for (int cam = 0; cam < N_; ++cam) {
        const int cb = ((cam * ZC_ + zg) * YC_ + y0_) * XC_ + xg;
        gx[cam]  = coords[cb * 3 + 0];
        gy[cam]  = coords[cb * 3 + 1];
        gzv[cam] = coords[cb * 3 + 2];
        mm[cam]  = validm[cb];
        ms[p0][cam] = mm[cam];
    }
    __syncthreads();

    // ---- phase 0b: packed weights + offsets + activity bits ----
    {
        const float inv = 1.0f / (ms[p0][0] + ms[p0][1] + ms[p0][2] + ms[p0][3] + EPS_);
        #pragma unroll
        for (int cam = 0; cam < N_; ++cam) {
            const float xf = ((gx[cam] + 1.0f) * (float)W_ - 1.0f) * 0.5f;
            const float yf = ((gy[cam] + 1.0f) * (float)H_ - 1.0f) * 0.5f;
            const float zf = gzv[cam] * 0.5f;
            const float x0f = floorf(xf), y0f = floorf(yf), z0f = floorf(zf);
            const float wx = xf - x0f, wy = yf - y0f, wz = zf - z0f;
            const int xi = (int)x0f, yi = (int)y0f, zi = (int)z0f;

            const float zw = (zi == 0) ? (1.f - wz) : ((zi == -1) ? wz : 0.f);
            const float s  = mm[cam] * zw * inv;

            const float wx0 = (xi >= 0 && xi < W_)         ? (1.f - wx) * s : 0.f;
            const float wx1 = (xi + 1 >= 0 && xi + 1 < W_) ? wx * s         : 0.f;
            const float wy0 = (yi >= 0 && yi < H_)         ? (1.f - wy)     : 0.f;
            const float wy1 = (yi + 1 >= 0 && yi + 1 < H_) ? wy             : 0.f;

            const unsigned q00 = (unsigned)(wy0 * wx0 * 4095.f + 0.5f);
            const unsigned q01 = (unsigned)(wy0 * wx1 * 4095.f + 0.5f);
            const unsigned q10 = (unsigned)(wy1 * wx0 * 4095.f + 0.5f);
            const unsigned q11 = (unsigned)(wy1 * wx1 * 4095.f + 0.5f);

            const int xc0 = min(max(xi, 0), W_ - 1);
            const int xc1 = min(max(xi + 1, 0), W_ - 1);
            const int yc0 = min(max(yi, 0), H_ - 1);
            const int yc1 = min(max(yi + 1, 0), H_ - 1);
            const unsigned pixidx = (unsigned)((cam * H_ + yc0) * W_ + xc0);  // <6720
            const unsigned fdx = (unsigned)(xc1 - xc0);   // 0/1
            const unsigned fdy = (unsigned)(yc1 - yc0);   // 0/1

            const unsigned A = q00 | (q01 << 12) | ((q10 & 0xFFu) << 24);
            const unsigned B = (q10 >> 8) | (q11 << 4) | (pixidx << 16)
                             | (fdx << 29) | (fdy << 30);
            tab2[cam * 256 + p0] = make_uint2(A, B);

            if (q00 | q01 | q10 | q11)
                atomicOr(&cmaskA[col0], 1u << (y0_ * 4 + cam));
        }
    }
    __syncthreads();

    // ---- read activity mask, then release the aliased region ----
    const int grp   = t >> 3;        // 0..31 == column
    const int lane8 = t & 7;
    const unsigned cm = cmaskA[grp];
    __syncthreads();

    const unsigned lb = (unsigned)(lane8 << 4);
    const char* fb = (const char*)featB;

    // ---- sampling: iterate only active (y,cam) items via ctz ----
    #pragma unroll
    for (int y = 0; y < YC_; ++y) {
        const int p    = y * 32 + grp;
        const int kb   = y * 8 + lane8;
        const int pcol = (grp & 16) | ((grp ^ kb) & 15);   // XOR swizzle

        unsigned sub = (cm >> (y * 4)) & 0xFu;
        uint4 R = make_uint4(0u, 0u, 0u, 0u);

        if (sub) {
            float2 num[4] = {{0.f,0.f},{0.f,0.f},{0.f,0.f},{0.f,0.f}};
            while (sub) {
                const int cam = __builtin_ctz(sub);
                sub &= sub - 1u;
                const uint2 T = tab2[cam * 256 + p];
                const float w00 = (float)(T.x & 0xFFFu)                      * (1.f/4095.f);
                const float w01 = (float)((T.x >> 12) & 0xFFFu)              * (1.f/4095.f);
                const float w10 = (float)((T.x >> 24) | ((T.y & 0xFu) << 8)) * (1.f/4095.f);
                const float w11 = (float)((T.y >> 4) & 0xFFFu)               * (1.f/4095.f);
                const unsigned base = (((T.y >> 16) & 0x1FFFu) << 7) + lb;
                const unsigned dxo  = ((T.y >> 29) & 1u) << 7;
                const unsigned dyo  = ((T.y >> 30) & 1u) * (unsigned)(W_ * 128);
                const uint4 V0 = *(const uint4*)(fb + base);
                const uint4 V1 = *(const uint4*)(fb + (base + dxo));
                const uint4 V2 = *(const uint4*)(fb + (base + dyo));
                const uint4 V3 = *(const uint4*)(fb + (base + dyo + dxo));
                accp(num, V0, w00);
                accp(num, V1, w01);
                accp(num, V2, w10);
                accp(num, V3, w11);
            }
            unsigned r0, r1, r2, r3;
            asm("v_cvt_pk_bf16_f32 %0, %1, %2" : "=v"(r0) : "v"(num[0].x), "v"(num[0].y));
            asm("v_cvt_pk_bf16_f32 %0, %1, %2" : "=v"(r1) : "v"(num[1].x), "v"(num[1].y));
            asm("v_cvt_pk_bf16_f32 %0, %1, %2" : "=v"(r2) : "v"(num[2].x), "v"(num[2].y));
            asm("v_cvt_pk_bf16_f32 %0, %1, %2" : "=v"(r3) : "v"(num[3].x), "v"(num[3].y));
            R = make_uint4(r0, r1, r2, r3);
        }
        *(uint4*)&redB[kb][pcol][0] = R;
    }
    __syncthreads();

    // ---- GEMM: C[128,32] = Wb[128,512] * redB[512,32] ----
    const int wave = t >> 6;        // 0..3 -> rows [wave*32, +32)
    const int lane = t & 63;
    const int q    = lane >> 4;     // 0..3
    const int l16  = lane & 15;

    f32x4 acc00 = {0.f,0.f,0.f,0.f}, acc01 = {0.f,0.f,0.f,0.f};
    f32x4 acc10 = {0.f,0.f,0.f,0.f}, acc11 = {0.f,0.f,0.f,0.f};
    const unsigned short* wbase = Wb + (wave * 32 + l16) * KD_;

    #pragma unroll
    for (int ks = 0; ks < 16; ++ks) {
        const int kb = ks * 4 + q;
        const int xs = l16 ^ (kb & 15);
        const short8 B0 = *(const short8*)&redB[kb][xs][0];
        const short8 B1 = *(const short8*)&redB[kb][16 + xs][0];
        const short8 A0 = *(const short8*)(wbase + ks * 32 + q * 8);
        const short8 A1 = *(const short8*)(wbase + 16 * KD_ + ks * 32 + q * 8);
        acc00 = __builtin_amdgcn_mfma_f32_16x16x32_bf16(A0, B0, acc00, 0, 0, 0);
        acc01 = __builtin_amdgcn_mfma_f32_16x16x32_bf16(A0, B1, acc01, 0, 0, 0);
        acc10 = __builtin_amdgcn_mfma_f32_16x16x32_bf16(A1, B0, acc10, 0, 0, 0);
        acc11 = __builtin_amdgcn_mfma_f32_16x16x32_bf16(A1, B1, acc11, 0, 0, 0);
    }

    #pragma unroll
    for (int ct = 0; ct < 2; ++ct) {
        const int col = ct * 16 + l16;
        const int zz  = col >> 3;
        const int xl  = col & 7;
        const int ob  = (z0 + zz) * XC_ + x0 + xl;
        const f32x4 a0 = ct ? acc01 : acc00;
        const f32x4 a1 = ct ? acc11 : acc10;
        #pragma unroll
        for (int j = 0; j < 4; ++j) {
            const int o0 = wave * 32 + q * 4 + j;
            out[o0 * (ZC_ * XC_) + ob] = a0[j] + bias[o0];
            const int o1 = o0 + 16;
            out[o1 * (ZC_ * XC_) + ob] = a1[j] + bias[o1];
        }
    }
}

extern "C" void kernel_launch(void* const* d_in, const int* in_sizes, int n_in,
                              void* d_out, int out_size, void* d_ws, size_t ws_size,
                              hipStream_t stream) {
    const float* coords = (const float*)d_in[0];   // (1,4,200,8,200,3)
    const float* validm = (const float*)d_in[1];   // (1,4,200,8,200,1)
    const float* img    = (const float*)d_in[2];   // (1,4,64,28,60)
    const float* Wc     = (const float*)d_in[3];   // (128, 512)
    const float* bias   = (const float*)d_in[4];   // (128)
    float* out = (float*)d_out;                    // (1,1,128,200,200)

    unsigned short* featB = (unsigned short*)d_ws;           // 430080 bf16
    unsigned short* Wb    = featB + (N_ * H_ * W_ * C_);     // 65536 bf16

    gsvt_prep<<<512, 256, 0, stream>>>(img, Wc, featB, Wb);

    dim3 grid(XC_ / XB, ZC_ / ZB);   // (25, 50)
    gsvt_fused2<<<grid, 256, 0, stream>>>(coords, validm, featB, Wb, bias, out);
}